// Round 1
// 166.615 us; speedup vs baseline: 1.0214x; 1.0214x over previous
//
#include <hip/hip_runtime.h>
#include <hip/hip_bf16.h>
#include <math.h>

#define Bn 8
#define Cn 1152
#define Nn 1024  // H*W

typedef short short8 __attribute__((ext_vector_type(8)));
typedef float f32x4 __attribute__((ext_vector_type(4)));

// Softmax/GEMM intermediates. Fully overwritten every call.
__device__ float g_csum_part[Bn * 32 * Nn];  // per-(b, seg) partial column sums
__device__ unsigned short g_A[(size_t)Bn * Nn * Nn];   // E[b][i][j] = exp(w) (unnormalized)
__device__ unsigned short g_fb[(size_t)Bn * Cn * Nn];  // f_src[b][c][j] / csum[b][j] in bf16

__device__ inline unsigned short f2bf(float x) {
    __hip_bfloat16 h = __float2bfloat16(x);
    unsigned short u;
    __builtin_memcpy(&u, &h, 2);
    return u;
}

__device__ inline void inv3(const float* M, float* o) {
    float a = M[0], b = M[1], c = M[2];
    float d = M[3], e = M[4], f = M[5];
    float g = M[6], h = M[7], i = M[8];
    float A0 = (e * i - f * h);
    float A1 = -(d * i - f * g);
    float A2 = (d * h - e * g);
    float det = a * A0 + b * A1 + c * A2;
    float inv = 1.0f / det;
    o[0] = A0 * inv;
    o[1] = -(b * i - c * h) * inv;
    o[2] = (b * f - c * e) * inv;
    o[3] = A1 * inv;
    o[4] = (a * i - c * g) * inv;
    o[5] = -(a * f - c * d) * inv;
    o[6] = A2 * inv;
    o[7] = -(a * h - b * g) * inv;
    o[8] = (a * e - b * d) * inv;
}

__device__ inline void mm3(const float* X, const float* Y, float* Z) {
    for (int r = 0; r < 3; r++)
        for (int c = 0; c < 3; c++)
            Z[r * 3 + c] = X[r * 3 + 0] * Y[0 * 3 + c] + X[r * 3 + 1] * Y[1 * 3 + c] +
                           X[r * 3 + 2] * Y[2 * 3 + c];
}

// F = inv(K2^T) skew(t) R inv(K1). SVD in the reference is a rank-2 no-op
// (skew(t)@R already has singular values (|t|,|t|,0)). Thread 0 per block.
__device__ inline void computeF(const float* K1, const float* K2, const float* R,
                                const float* t, int b, float* F) {
    float t0 = t[b * 3 + 0], t1 = t[b * 3 + 1], t2 = t[b * 3 + 2];
    float S[9] = {0.0f, -t2, t1, t2, 0.0f, -t0, -t1, t0, 0.0f};
    float E[9];
    mm3(S, &R[b * 9], E);
    float iK1[9], iK2[9];
    inv3(&K1[b * 9], iK1);
    inv3(&K2[b * 9], iK2);
    float iK2T[9] = {iK2[0], iK2[3], iK2[6], iK2[1], iK2[4], iK2[7], iK2[2], iK2[5], iK2[8]};
    float T[9];
    mm3(iK2T, E, T);
    mm3(T, iK1, F);
}

// Per-j coefficients: z_ij = |ix*P + iy*Q - R| - 0.5  (== 5*(d_epi - 0.1))
__device__ inline float4 zcoef(const float* F, int j) {
    float jx = (float)(j >> 5);
    float jy = (float)(j & 31);
    float l0 = F[0] * jx + F[1] * jy + F[2];
    float l1 = F[3] * jx + F[4] * jy + F[5];
    float l2 = F[6] * jx + F[7] * jy + F[8];
    l0 = l0 / l2;
    l1 = l1 / l2;
    float y0 = -1.0f / l1;
    float y1 = -(1.0f + l0 * 32.0f) / l1;
    float dy = y0 - y1;
    float invn = 1.0f / sqrtf(1024.0f + dy * dy);
    return make_float4(5.0f * dy * invn, 160.0f * invn, 160.0f * y0 * invn, 0.0f);
}

// Fused prep: per (b, seg) block of 32 rows, compute z once per (i,j), do the
// row softmax in-wave (full row per wave, lane owns j = lane+64k), emit
// E = exp(1 - rowsoftmax) as bf16 + per-(b,seg) partial column sums.
// Replaces the old rowstats+colE pair (which computed every z twice and
// round-tripped rmax/rsuminv through HBM). Grid 256: lin&7 = b = XCD.
__launch_bounds__(256) __global__ void fusedE_kernel(const float* __restrict__ K1,
                                                     const float* __restrict__ K2,
                                                     const float* __restrict__ R,
                                                     const float* __restrict__ t) {
    __shared__ float Fs[9];
    __shared__ float4 prm[Nn];        // 16 KB
    __shared__ float red[4][16][64];  // 16 KB, per-wave csum partials
    int lin = blockIdx.x;
    int b = lin & 7;
    int seg = lin >> 3;  // 0..31
    if (threadIdx.x == 0) computeF(K1, K2, R, t, b, Fs);
    __syncthreads();
#pragma unroll
    for (int u = 0; u < 4; u++) {
        int j = threadIdx.x * 4 + u;
        prm[j] = zcoef(Fs, j);
    }
    __syncthreads();
    int wv = threadIdx.x >> 6;
    int lane = threadIdx.x & 63;
    // Hoist this lane's 16 line coefficients into registers (read LDS once,
    // not once per row as the old rowstats did).
    float px[16], py[16], pz[16];
#pragma unroll
    for (int k = 0; k < 16; k++) {
        float4 p = prm[lane + k * 64];
        px[k] = p.x;
        py[k] = p.y;
        pz[k] = p.z;
    }
    float csum[16];
#pragma unroll
    for (int k = 0; k < 16; k++) csum[k] = 0.0f;
#pragma unroll
    for (int rr = 0; rr < 8; rr++) {
        int i = seg * 32 + wv * 8 + rr;
        float ix = (float)(i >> 5), iy = (float)(i & 31);
        float e[16], m = -INFINITY;
#pragma unroll
        for (int k = 0; k < 16; k++) {
            e[k] = fabsf(fmaf(ix, px[k], fmaf(iy, py[k], -pz[k]))) - 0.5f;
            m = fmaxf(m, e[k]);
        }
#pragma unroll
        for (int o = 32; o > 0; o >>= 1) m = fmaxf(m, __shfl_xor(m, o, 64));
        float s = 0.0f;
#pragma unroll
        for (int k = 0; k < 16; k++) {
            e[k] = __expf(e[k] - m);  // reused below: saves 16 exps/row vs colE
            s += e[k];
        }
#pragma unroll
        for (int o = 32; o > 0; o >>= 1) s += __shfl_xor(s, o, 64);
        float rsi = 1.0f / s;
        unsigned short* arow = g_A + (size_t)(b * Nn + i) * Nn;
#pragma unroll
        for (int k = 0; k < 16; k++) {
            float E = __expf(1.0f - e[k] * rsi);
            csum[k] += E;
            arow[lane + k * 64] = f2bf(E);
        }
    }
#pragma unroll
    for (int k = 0; k < 16; k++) red[wv][k][lane] = csum[k];
    __syncthreads();
    // Cross-wave reduce: thread tt handles 4 k's at its lane column.
    int l2 = threadIdx.x & 63;
    int k0 = (threadIdx.x >> 6) * 4;
#pragma unroll
    for (int q = 0; q < 4; q++) {
        int k = k0 + q;
        float ssum = red[0][k][l2] + red[1][k][l2] + red[2][k][l2] + red[3][k][l2];
        g_csum_part[(b * 32 + seg) * Nn + k * 64 + l2] = ssum;
    }
}

// f_src fp32 -> bf16 scaled by 1/csum[b][j], 8 channels per block (csum loaded once).
// Grid 1152: lin&7 = b = XCD, cg = lin>>3 (0..143) = 8-channel group.
__global__ void convert_fsrc_kernel(const float* __restrict__ f) {
    int lin = blockIdx.x;
    int b = lin & 7;
    int cg = lin >> 3;
    int j0 = threadIdx.x * 4;
    float4 cs = *(const float4*)&g_csum_part[(b * 32 + 0) * Nn + j0];
#pragma unroll
    for (int it = 1; it < 32; it++) {
        float4 p = *(const float4*)&g_csum_part[(b * 32 + it) * Nn + j0];
        cs.x += p.x; cs.y += p.y; cs.z += p.z; cs.w += p.w;
    }
    float4 inv = make_float4(1.0f / cs.x, 1.0f / cs.y, 1.0f / cs.z, 1.0f / cs.w);
#pragma unroll
    for (int c8 = 0; c8 < 8; c8++) {
        int c = cg * 8 + c8;
        size_t off = ((size_t)b * Cn + c) * Nn + j0;
        float4 v = *(const float4*)(f + off);
        ushort4 u;
        u.x = f2bf(v.x * inv.x);
        u.y = f2bf(v.y * inv.y);
        u.z = f2bf(v.z * inv.z);
        u.w = f2bf(v.w * inv.w);
        *(ushort4*)&g_fb[off] = u;
    }
}

// out[b,i,c] = sum_j E[b,i,j] * fb_scaled[b,c,j]  — both operands K(j)-contiguous.
// m97 structure: 128(i) x 128(c) block-tile, 256 threads = 4 waves, each wave a
// 64x64 sub-tile (4x4 mfma_16x16x32). Double-buffered LDS (32 KB); 576 blocks;
// lin&7 = b = XCD so per-batch A (2 MB) + fb (2.36 MB) mostly stay in that
// XCD's 4 MB L2. Same k-quad XOR swizzle as the verified 128x64 version.
#define BM 128
#define BNc 128
#define BK 32

__launch_bounds__(256, 2) __global__ void gemm_kernel(float* __restrict__ out) {
    __shared__ unsigned short As[2][BM * BK];   // 8 KB each
    __shared__ unsigned short Bs[2][BNc * BK];  // 8 KB each
    int lin = blockIdx.x;
    int b = lin & 7;
    int s = lin >> 3;  // 0..71
    int it = s & 7;    // 0..7
    int ct = s >> 3;   // 0..8
    int i0 = it * BM;
    int c0 = ct * BNc;
    int t = threadIdx.x;
    int w = t >> 6, L = t & 63;
    int wr = w >> 1, wc = w & 1;  // wave -> 64x64 quadrant of the 128x128 tile
    const unsigned short* Ab = g_A + (size_t)b * Nn * Nn + (size_t)i0 * Nn;
    const unsigned short* Fb = g_fb + (size_t)b * Cn * Nn + (size_t)c0 * Nn;

    auto stage = [&](int p, int kt) {
        // A and B: 512 x 16B chunks each, 2/thread each
#pragma unroll
        for (int h = 0; h < 2; h++) {
            int chunk = h * 256 + t;                 // 0..511
            int rr = chunk >> 2;                     // row 0..127
            int gq = (chunk & 3) ^ ((rr >> 1) & 3);  // swizzled global k-quad
            const unsigned short* ga = Ab + (size_t)rr * Nn + kt + gq * 8;
            __builtin_amdgcn_global_load_lds(
                (const __attribute__((address_space(1))) unsigned int*)ga,
                (__attribute__((address_space(3))) unsigned int*)(As[p] + chunk * 8), 16, 0, 0);
            const unsigned short* gb = Fb + (size_t)rr * Nn + kt + gq * 8;
            __builtin_amdgcn_global_load_lds(
                (const __attribute__((address_space(1))) unsigned int*)gb,
                (__attribute__((address_space(3))) unsigned int*)(Bs[p] + chunk * 8), 16, 0, 0);
        }
    };

    f32x4 acc[4][4] = {};
    int lrow = L & 15, quad = L >> 4;
    stage(0, 0);
    for (int kt = 0; kt < Nn; kt += BK) {
        int p = (kt >> 5) & 1;
        __syncthreads();  // vmcnt(0): buffer p staged; prev compute retired
        if (kt + BK < Nn) stage(1 - p, kt + BK);  // in flight during compute below
        short8 af[4], bf[4];
#pragma unroll
        for (int mt = 0; mt < 4; mt++) {
            int rr = wr * 64 + mt * 16 + lrow;
            int q = quad ^ ((rr >> 1) & 3);
            af[mt] = *(const short8*)(As[p] + rr * BK + q * 8);
        }
#pragma unroll
        for (int nt = 0; nt < 4; nt++) {
            int cc = wc * 64 + nt * 16 + lrow;
            int q = quad ^ ((cc >> 1) & 3);
            bf[nt] = *(const short8*)(Bs[p] + cc * BK + q * 8);
        }
#pragma unroll
        for (int mt = 0; mt < 4; mt++)
#pragma unroll
            for (int nt = 0; nt < 4; nt++)
                acc[mt][nt] =
                    __builtin_amdgcn_mfma_f32_16x16x32_bf16(af[mt], bf[nt], acc[mt][nt], 0, 0, 0);
    }
    // Epilogue: D col=lane&15, row=(lane>>4)*4+reg  [m89-verified]
    int col = L & 15;
#pragma unroll
    for (int mt = 0; mt < 4; mt++)
#pragma unroll
        for (int rg = 0; rg < 4; rg++) {
            int i = i0 + wr * 64 + mt * 16 + quad * 4 + rg;
            float* orow = out + ((size_t)b * Nn + i) * Cn + c0 + wc * 64;
#pragma unroll
            for (int nt = 0; nt < 4; nt++) orow[nt * 16 + col] = acc[mt][nt][rg];
        }
}

extern "C" void kernel_launch(void* const* d_in, const int* in_sizes, int n_in,
                              void* d_out, int out_size, void* d_ws, size_t ws_size,
                              hipStream_t stream) {
    (void)in_sizes; (void)n_in; (void)d_ws; (void)ws_size; (void)out_size;
    const float* f_src = (const float*)d_in[1];  // d_in[0] = f_tar unused by reference
    const float* K1 = (const float*)d_in[2];
    const float* K2 = (const float*)d_in[3];
    const float* R = (const float*)d_in[4];
    const float* t = (const float*)d_in[5];
    float* out = (float*)d_out;

    fusedE_kernel<<<dim3(256), dim3(256), 0, stream>>>(K1, K2, R, t);
    convert_fsrc_kernel<<<dim3(Bn * Cn / 8), dim3(256), 0, stream>>>(f_src);
    gemm_kernel<<<dim3(Bn * (Nn / BM) * (Cn / BNc)), dim3(256), 0, stream>>>(out);
}